// Round 1
// baseline (1315.802 us; speedup 1.0000x reference)
//
#include <hip/hip_runtime.h>
#include <hip/hip_bf16.h>

#define H 128
#define W 256
#define HW (H*W)
#define NC 32
#define ND 32
#define NHID 64

// ---------------- generic 3x3 same-pad conv, tiled, 8 couts per block ----------------
__global__ void conv3x3(const float* __restrict__ in, float* __restrict__ out,
                        const float* __restrict__ w, const float* __restrict__ b,
                        int CIN, int COUT, int wstride, int dorelu) {
    __shared__ float tile[10][35];
    int tid = threadIdx.x;
    int gx0 = blockIdx.x * 32, gy0 = blockIdx.y * 8;
    int cobase = blockIdx.z * 8;
    int tx = tid & 31, ty = tid >> 5;
    float acc[8];
#pragma unroll
    for (int i = 0; i < 8; i++) acc[i] = 0.f;
    for (int c = 0; c < CIN; c++) {
        for (int i = tid; i < 340; i += 256) {
            int r = i / 34, cc = i % 34;
            int gy = gy0 + r - 1, gx = gx0 + cc - 1;
            tile[r][cc] = (gy >= 0 && gy < H && gx >= 0 && gx < W) ? in[c * HW + gy * W + gx] : 0.f;
        }
        __syncthreads();
        float v[9];
#pragma unroll
        for (int ky = 0; ky < 3; ky++)
#pragma unroll
            for (int kx = 0; kx < 3; kx++)
                v[ky * 3 + kx] = tile[ty + ky][tx + kx];
#pragma unroll
        for (int i = 0; i < 8; i++) {
            int co = cobase + i;
            if (co < COUT) {
                const float* wp = w + (size_t)co * wstride + c * 9;
#pragma unroll
                for (int k = 0; k < 9; k++) acc[i] += wp[k] * v[k];
            }
        }
        __syncthreads();
    }
    int gy = gy0 + ty, gx = gx0 + tx;
#pragma unroll
    for (int i = 0; i < 8; i++) {
        int co = cobase + i;
        if (co < COUT) {
            float r = acc[i] + b[co];
            if (dorelu) r = fmaxf(r, 0.f);
            out[co * HW + gy * W + gx] = r;
        }
    }
}

// ---------------- per-pixel channel dot for cost volume separation ----------------
__global__ void chan_dot(const float* __restrict__ lf, const float* __restrict__ rf,
                         const float* __restrict__ cvw,
                         float* __restrict__ lsum, float* __restrict__ rsum) {
    int p = blockIdx.x * 256 + threadIdx.x;
    if (p >= HW) return;
    float ls = 0.f, rs = 0.f;
    for (int c = 0; c < NC; c++) {
        ls += lf[c * HW + p] * cvw[c];
        rs += rf[c * HW + p] * cvw[NC + c];
    }
    lsum[p] = ls;
    rsum[p] = rs;
}

// ---------------- cost[d,h,w] = lsum + shift(rsum, d) + cv_b; belief init ----------------
__global__ void cost_expand(const float* __restrict__ lsum, const float* __restrict__ rsum,
                            const float* __restrict__ cvb,
                            float* __restrict__ cost, float* __restrict__ bel) {
    int idx = blockIdx.x * 256 + threadIdx.x;
    if (idx >= ND * HW) return;
    int d = idx / HW, p = idx % HW;
    int col = p & (W - 1);
    float c = lsum[p] + cvb[0];
    if (col >= d) c += rsum[p - d];
    cost[idx] = c;
    bel[idx] = c;
}

// ---------------- fused MP iteration: belief -> hdn (chunked in LDS) -> msg -> new belief ----------------
__global__ void mp_iter(const float* __restrict__ A, const float* __restrict__ cost,
                        const float* __restrict__ bin, float* __restrict__ bout,
                        const float* __restrict__ mp_w1, const float* __restrict__ mp_w2,
                        const float* __restrict__ mp_b2) {
    __shared__ float bel[12][37];
    __shared__ float hdn[16][10][35];
    __shared__ float w1b[64][9];
    __shared__ float w2s[64][9];
    int tid = threadIdx.x;
    int d = blockIdx.z;
    int gx0 = blockIdx.x * 32, gy0 = blockIdx.y * 8;
    const float* beld = bin + (size_t)d * HW;
    for (int i = tid; i < 64 * 9; i += 256) {
        int hid = i / 9, k = i % 9;
        w1b[hid][k] = mp_w1[(size_t)hid * 297 + 32 * 9 + k];
        w2s[hid][k] = mp_w2[i];
    }
    for (int i = tid; i < 12 * 36; i += 256) {
        int r = i / 36, c = i % 36;
        int gy = gy0 + r - 2, gx = gx0 + c - 2;
        bel[r][c] = (gy >= 0 && gy < H && gx >= 0 && gx < W) ? beld[gy * W + gx] : 0.f;
    }
    __syncthreads();
    int tx = tid & 31, ty = tid >> 5;
    float msg = 0.f;
    for (int hc = 0; hc < 4; ++hc) {
        for (int i = tid; i < 16 * 340; i += 256) {
            int hi = i / 340, rem = i % 340;
            int y = rem / 34, x = rem % 34;
            int hid = hc * 16 + hi;
            int gy = gy0 + y - 1, gx = gx0 + x - 1;
            float v = 0.f;
            if (gy >= 0 && gy < H && gx >= 0 && gx < W) {
                float s = A[(size_t)hid * HW + gy * W + gx];
#pragma unroll
                for (int ky = 0; ky < 3; ky++)
#pragma unroll
                    for (int kx = 0; kx < 3; kx++)
                        s += w1b[hid][ky * 3 + kx] * bel[y + ky][x + kx];
                v = fmaxf(s, 0.f);
            }
            hdn[hi][y][x] = v;
        }
        __syncthreads();
#pragma unroll
        for (int hi = 0; hi < 16; hi++) {
            int hid = hc * 16 + hi;
#pragma unroll
            for (int ky = 0; ky < 3; ky++)
#pragma unroll
                for (int kx = 0; kx < 3; kx++)
                    msg += w2s[hid][ky * 3 + kx] * hdn[hi][ty + ky][tx + kx];
        }
        __syncthreads();
    }
    int gy = gy0 + ty, gx = gx0 + tx;
    size_t o = (size_t)d * HW + gy * W + gx;
    bout[o] = cost[o] + msg + mp_b2[0];
}

// ---------------- softmax over D of -belief, expectation of d ----------------
__global__ void softmax_disp(const float* __restrict__ bel, float* __restrict__ disp) {
    int p = blockIdx.x * 256 + threadIdx.x;
    if (p >= HW) return;
    float v[ND];
    float m = -1e30f;
#pragma unroll
    for (int d = 0; d < ND; d++) {
        v[d] = -bel[d * HW + p];
        m = fmaxf(m, v[d]);
    }
    float s = 0.f, ws = 0.f;
#pragma unroll
    for (int d = 0; d < ND; d++) {
        float e = __expf(v[d] - m);
        s += e;
        ws += e * (float)d;
    }
    disp[p] = ws / s;
}

// ---------------- concat left_img(3ch) + disparity -> 4ch ----------------
__global__ void concat4(const float* __restrict__ left, const float* __restrict__ disp,
                        float* __restrict__ x4) {
    int idx = blockIdx.x * 256 + threadIdx.x;
    if (idx >= 4 * HW) return;
    int c = idx / HW, p = idx % HW;
    x4[idx] = (c < 3) ? left[idx] : disp[p];
}

// ---------------- out = disp + res ----------------
__global__ void final_add(const float* __restrict__ disp, const float* __restrict__ res,
                          float* __restrict__ out) {
    int p = blockIdx.x * 256 + threadIdx.x;
    if (p >= HW) return;
    out[p] = disp[p] + res[p];
}

extern "C" void kernel_launch(void* const* d_in, const int* in_sizes, int n_in,
                              void* d_out, int out_size, void* d_ws, size_t ws_size,
                              hipStream_t stream) {
    const float* left   = (const float*)d_in[0];
    const float* right  = (const float*)d_in[1];
    const float* fe_w1  = (const float*)d_in[2];
    const float* fe_b1  = (const float*)d_in[3];
    const float* fe_w2  = (const float*)d_in[4];
    const float* fe_b2  = (const float*)d_in[5];
    const float* cv_w   = (const float*)d_in[6];
    const float* cv_b   = (const float*)d_in[7];
    const float* mp_w1  = (const float*)d_in[8];
    const float* mp_b1  = (const float*)d_in[9];
    const float* mp_w2  = (const float*)d_in[10];
    const float* mp_b2  = (const float*)d_in[11];
    const float* rf_w1  = (const float*)d_in[12];
    const float* rf_b1  = (const float*)d_in[13];
    const float* rf_w2  = (const float*)d_in[14];
    const float* rf_b2  = (const float*)d_in[15];
    const float* rf_w3  = (const float*)d_in[16];
    const float* rf_b3  = (const float*)d_in[17];
    float* out = (float*)d_out;

    float* ws = (float*)d_ws;
    // layout (floats)
    float* A     = ws;                          // 64*HW = 2,097,152 (tmp & r1 alias here)
    float* tmp   = ws;                          // alias inside A region (1,048,576 used)
    float* lf    = ws + 2097152;                // 32*HW
    float* rfeat = ws + 3145728;                // 32*HW (r2 aliases later)
    float* cost  = ws + 4194304;                // 32*HW
    float* bel   = ws + 5242880;                // 32*HW
    float* bel2  = ws + 6291456;                // 32*HW
    float* lsum  = ws + 7340032;                // HW
    float* rsum  = ws + 7372800;                // HW
    float* disp  = ws + 7405568;                // HW
    float* x4    = ws + 7438336;                // 4*HW
    float* res   = ws + 7569408;                // HW

    dim3 blk(256);
    dim3 gconv(8, 16, 4);   // COUT=32
    dim3 gconv64(8, 16, 8); // COUT=64
    dim3 gconv1(8, 16, 1);  // COUT=1

    // feature extraction
    conv3x3<<<gconv, blk, 0, stream>>>(left, tmp, fe_w1, fe_b1, 3, 32, 27, 1);
    conv3x3<<<gconv, blk, 0, stream>>>(tmp, lf, fe_w2, fe_b2, 32, 32, 288, 1);
    conv3x3<<<gconv, blk, 0, stream>>>(right, tmp, fe_w1, fe_b1, 3, 32, 27, 1);
    conv3x3<<<gconv, blk, 0, stream>>>(tmp, rfeat, fe_w2, fe_b2, 32, 32, 288, 1);

    // cost volume (separated)
    chan_dot<<<dim3(HW / 256), blk, 0, stream>>>(lf, rfeat, cv_w, lsum, rsum);

    // hoisted lf-part of mp conv1 (includes mp_b1, no relu)
    conv3x3<<<gconv64, blk, 0, stream>>>(lf, A, mp_w1, mp_b1, 32, 64, 297, 0);

    cost_expand<<<dim3(ND * HW / 256), blk, 0, stream>>>(lsum, rsum, cv_b, cost, bel);

    // 5 MP iterations, ping-pong
    dim3 gmp(8, 16, ND);
    mp_iter<<<gmp, blk, 0, stream>>>(A, cost, bel,  bel2, mp_w1, mp_w2, mp_b2);
    mp_iter<<<gmp, blk, 0, stream>>>(A, cost, bel2, bel,  mp_w1, mp_w2, mp_b2);
    mp_iter<<<gmp, blk, 0, stream>>>(A, cost, bel,  bel2, mp_w1, mp_w2, mp_b2);
    mp_iter<<<gmp, blk, 0, stream>>>(A, cost, bel2, bel,  mp_w1, mp_w2, mp_b2);
    mp_iter<<<gmp, blk, 0, stream>>>(A, cost, bel,  bel2, mp_w1, mp_w2, mp_b2);

    softmax_disp<<<dim3(HW / 256), blk, 0, stream>>>(bel2, disp);

    // refinement
    concat4<<<dim3(4 * HW / 256), blk, 0, stream>>>(left, disp, x4);
    conv3x3<<<gconv, blk, 0, stream>>>(x4, A, rf_w1, rf_b1, 4, 32, 36, 1);        // r1 -> A region
    conv3x3<<<gconv, blk, 0, stream>>>(A, rfeat, rf_w2, rf_b2, 32, 32, 288, 1);   // r2 -> rfeat region
    conv3x3<<<gconv1, blk, 0, stream>>>(rfeat, res, rf_w3, rf_b3, 32, 1, 288, 0);

    final_add<<<dim3(HW / 256), blk, 0, stream>>>(disp, res, out);
}

// Round 2
// 752.810 us; speedup vs baseline: 1.7479x; 1.7479x over previous
//
#include <hip/hip_runtime.h>
#include <hip/hip_bf16.h>

#define H 128
#define W 256
#define HW (H*W)
#define NC 32
#define ND 32
#define NHID 64

// ---------------- generic 3x3 same-pad conv, tiled, 8 couts per block ----------------
__global__ void conv3x3(const float* __restrict__ in, float* __restrict__ out,
                        const float* __restrict__ w, const float* __restrict__ b,
                        int CIN, int COUT, int wstride, int dorelu) {
    __shared__ float tile[10][35];
    int tid = threadIdx.x;
    int gx0 = blockIdx.x * 32, gy0 = blockIdx.y * 8;
    int cobase = blockIdx.z * 8;
    int tx = tid & 31, ty = tid >> 5;
    float acc[8];
#pragma unroll
    for (int i = 0; i < 8; i++) acc[i] = 0.f;
    for (int c = 0; c < CIN; c++) {
        for (int i = tid; i < 340; i += 256) {
            int r = i / 34, cc = i % 34;
            int gy = gy0 + r - 1, gx = gx0 + cc - 1;
            tile[r][cc] = (gy >= 0 && gy < H && gx >= 0 && gx < W) ? in[c * HW + gy * W + gx] : 0.f;
        }
        __syncthreads();
        float v[9];
#pragma unroll
        for (int ky = 0; ky < 3; ky++)
#pragma unroll
            for (int kx = 0; kx < 3; kx++)
                v[ky * 3 + kx] = tile[ty + ky][tx + kx];
#pragma unroll
        for (int i = 0; i < 8; i++) {
            int co = cobase + i;
            if (co < COUT) {
                const float* wp = w + (size_t)co * wstride + c * 9;
#pragma unroll
                for (int k = 0; k < 9; k++) acc[i] += wp[k] * v[k];
            }
        }
        __syncthreads();
    }
    int gy = gy0 + ty, gx = gx0 + tx;
#pragma unroll
    for (int i = 0; i < 8; i++) {
        int co = cobase + i;
        if (co < COUT) {
            float r = acc[i] + b[co];
            if (dorelu) r = fmaxf(r, 0.f);
            out[co * HW + gy * W + gx] = r;
        }
    }
}

// ---------------- per-pixel channel dot for cost volume separation ----------------
__global__ void chan_dot(const float* __restrict__ lf, const float* __restrict__ rf,
                         const float* __restrict__ cvw,
                         float* __restrict__ lsum, float* __restrict__ rsum) {
    int p = blockIdx.x * 256 + threadIdx.x;
    if (p >= HW) return;
    float ls = 0.f, rs = 0.f;
    for (int c = 0; c < NC; c++) {
        ls += lf[c * HW + p] * cvw[c];
        rs += rf[c * HW + p] * cvw[NC + c];
    }
    lsum[p] = ls;
    rsum[p] = rs;
}

// ---------------- cost[d,h,w] = lsum + shift(rsum, d) + cv_b; belief init ----------------
__global__ void cost_expand(const float* __restrict__ lsum, const float* __restrict__ rsum,
                            const float* __restrict__ cvb,
                            float* __restrict__ cost, float* __restrict__ bel) {
    int idx = blockIdx.x * 256 + threadIdx.x;
    if (idx >= ND * HW) return;
    int d = idx / HW, p = idx % HW;
    int col = p & (W - 1);
    float c = lsum[p] + cvb[0];
    if (col >= d) c += rsum[p - d];
    cost[idx] = c;
    bel[idx] = c;
}

// ---------------- A[hid][p] -> At[p][hid] (LDS tile transpose) ----------------
__global__ void a_transpose(const float* __restrict__ A, float* __restrict__ At) {
    __shared__ float t[64][65];
    int p0 = blockIdx.x * 64;
    int tx = threadIdx.x & 63;
    int ty = threadIdx.x >> 6;   // 0..3
#pragma unroll
    for (int r = 0; r < 16; r++) {
        int hid = ty * 16 + r;
        t[tx][hid] = A[(size_t)hid * HW + p0 + tx];
    }
    __syncthreads();
#pragma unroll
    for (int r = 0; r < 16; r++) {
        int p = ty * 16 + r;
        At[(size_t)(p0 + p) * 64 + tx] = t[p][tx];
    }
}

// ---------------- fast MP iteration: lane = hid, rolling hdn rows in registers ----------------
// wave handles (d, 16-wide x strip, 16-row y sweep). weights in VGPRs.
// hdn row yc = y0+U computed into HARR[18] (x = x0-1 .. x0+16)
#define COMPUTE_HDN(U, HARR)                                                   \
  {                                                                            \
    const int yc_ = y0 + (U);                                                  \
    if (yc_ < 0 || yc_ >= H) {                                                 \
      _Pragma("unroll") for (int j = 0; j < 18; j++) HARR[j] = 0.f;            \
    } else {                                                                   \
      float bw_[3][3];                                                         \
      _Pragma("unroll") for (int r = 0; r < 3; r++) {                          \
        bw_[r][0] = belS[lw][(U) + 1 + r][0];                                  \
        bw_[r][1] = belS[lw][(U) + 1 + r][1];                                  \
      }                                                                        \
      const float* Ar_ = At + (size_t)yc_ * (W * 64) + lane;                   \
      _Pragma("unroll") for (int j = 0; j < 18; j++) {                         \
        int xc_ = x0 - 1 + j;                                                  \
        int xcl_ = xc_ < 0 ? 0 : (xc_ > W - 1 ? W - 1 : xc_);                  \
        float acc_ = Ar_[xcl_ * 64];                                           \
        _Pragma("unroll") for (int r = 0; r < 3; r++)                          \
          bw_[r][(j + 2) % 3] = belS[lw][(U) + 1 + r][j + 2];                  \
        _Pragma("unroll") for (int r = 0; r < 3; r++)                          \
          _Pragma("unroll") for (int c = 0; c < 3; c++)                        \
            acc_ += w1[r * 3 + c] * bw_[r][(j + c) % 3];                       \
        HARR[j] = fmaxf(acc_, 0.f);                                            \
      }                                                                        \
      if (x0 == 0) HARR[0] = 0.f;                                              \
      if (x0 == W - 16) HARR[17] = 0.f;                                        \
    }                                                                          \
  }

__global__ __launch_bounds__(256) void mp_iter_fast(
    const float* __restrict__ At,    // [HW][64]
    const float* __restrict__ cost,
    const float* __restrict__ bin,
    float* __restrict__ bout,
    const float* __restrict__ mp_w1,
    const float* __restrict__ mp_w2,
    const float* __restrict__ mp_b2) {
    __shared__ float belS[4][20][20];
    __shared__ float partS[4][16][65];

    const int tid = threadIdx.x;
    const int lane = tid & 63;       // = hid
    const int lw = tid >> 6;         // wave in block
    const int wid = blockIdx.x * 4 + lw;
    // d fastest so consecutive waves/blocks share the same A_t slice (L1/L2 reuse)
    const int d = wid & 31;
    const int r2 = wid >> 5;         // 0..127
    const int strip = r2 & 15;
    const int sweep = r2 >> 4;       // 0..7
    const int y0 = sweep * 16;
    const int x0 = strip * 16;

    // per-lane weights (hid = lane), loaded once
    float w1[9], w2[9];
#pragma unroll
    for (int k = 0; k < 9; k++) {
        w1[k] = mp_w1[lane * 297 + 288 + k];   // belief channel (index 32) of mp_w1[hid]
        w2[k] = mp_w2[lane * 9 + k];
    }
    const float b2 = mp_b2[0];

    // stage belief tile: rows y0-2..y0+17, cols x0-2..x0+17 (zero-padded)
    const float* beld = bin + (size_t)d * HW;
#pragma unroll
    for (int it = 0; it < 7; it++) {
        int i = it * 64 + lane;
        if (i < 400) {
            int r = i / 20, c = i % 20;
            int gy = y0 - 2 + r, gx = x0 - 2 + c;
            belS[lw][r][c] = (gy >= 0 && gy < H && gx >= 0 && gx < W) ? beld[gy * W + gx] : 0.f;
        }
    }
    __syncthreads();

    float h2[18], h1[18], h0[18];
    COMPUTE_HDN(-1, h2);
    COMPUTE_HDN(0, h1);

    for (int t = 0; t < 16; t++) {
        COMPUTE_HDN(t + 1, h0);
        // msg partials: lane's hid contribution to each of 16 output pixels
#pragma unroll
        for (int jo = 0; jo < 16; jo++) {
            float p = w2[0] * h2[jo] + w2[1] * h2[jo + 1] + w2[2] * h2[jo + 2]
                    + w2[3] * h1[jo] + w2[4] * h1[jo + 1] + w2[5] * h1[jo + 2]
                    + w2[6] * h0[jo] + w2[7] * h0[jo + 1] + w2[8] * h0[jo + 2];
            partS[lw][jo][lane] = p;
        }
        __syncthreads();
        // transpose-reduce 64 lanes -> 16 pixels
        {
            int p = lane & 15, q = lane >> 4;
            float s = 0.f;
#pragma unroll
            for (int j = 0; j < 16; j++) s += partS[lw][p][q * 16 + j];
            s += __shfl_xor(s, 16);
            s += __shfl_xor(s, 32);
            if (q == 0) {
                size_t o = (size_t)d * HW + (size_t)(y0 + t) * W + x0 + p;
                bout[o] = cost[o] + s + b2;
            }
        }
        __syncthreads();
        // shift history down one row
#pragma unroll
        for (int j = 0; j < 18; j++) { h2[j] = h1[j]; h1[j] = h0[j]; }
    }
}

// ---------------- softmax over D of -belief, expectation of d ----------------
__global__ void softmax_disp(const float* __restrict__ bel, float* __restrict__ disp) {
    int p = blockIdx.x * 256 + threadIdx.x;
    if (p >= HW) return;
    float v[ND];
    float m = -1e30f;
#pragma unroll
    for (int d = 0; d < ND; d++) {
        v[d] = -bel[d * HW + p];
        m = fmaxf(m, v[d]);
    }
    float s = 0.f, ws = 0.f;
#pragma unroll
    for (int d = 0; d < ND; d++) {
        float e = __expf(v[d] - m);
        s += e;
        ws += e * (float)d;
    }
    disp[p] = ws / s;
}

// ---------------- concat left_img(3ch) + disparity -> 4ch ----------------
__global__ void concat4(const float* __restrict__ left, const float* __restrict__ disp,
                        float* __restrict__ x4) {
    int idx = blockIdx.x * 256 + threadIdx.x;
    if (idx >= 4 * HW) return;
    int c = idx / HW, p = idx % HW;
    x4[idx] = (c < 3) ? left[idx] : disp[p];
}

// ---------------- out = disp + res ----------------
__global__ void final_add(const float* __restrict__ disp, const float* __restrict__ res,
                          float* __restrict__ out) {
    int p = blockIdx.x * 256 + threadIdx.x;
    if (p >= HW) return;
    out[p] = disp[p] + res[p];
}

extern "C" void kernel_launch(void* const* d_in, const int* in_sizes, int n_in,
                              void* d_out, int out_size, void* d_ws, size_t ws_size,
                              hipStream_t stream) {
    const float* left   = (const float*)d_in[0];
    const float* right  = (const float*)d_in[1];
    const float* fe_w1  = (const float*)d_in[2];
    const float* fe_b1  = (const float*)d_in[3];
    const float* fe_w2  = (const float*)d_in[4];
    const float* fe_b2  = (const float*)d_in[5];
    const float* cv_w   = (const float*)d_in[6];
    const float* cv_b   = (const float*)d_in[7];
    const float* mp_w1  = (const float*)d_in[8];
    const float* mp_b1  = (const float*)d_in[9];
    const float* mp_w2  = (const float*)d_in[10];
    const float* mp_b2  = (const float*)d_in[11];
    const float* rf_w1  = (const float*)d_in[12];
    const float* rf_b1  = (const float*)d_in[13];
    const float* rf_w2  = (const float*)d_in[14];
    const float* rf_b2  = (const float*)d_in[15];
    const float* rf_w3  = (const float*)d_in[16];
    const float* rf_b3  = (const float*)d_in[17];
    float* out = (float*)d_out;

    float* ws = (float*)d_ws;
    // layout (floats):
    float* At    = ws;                  // 2M floats [HW][64]; also fe tmp (1M) earlier, r1 (1M) later
    float* tmp   = ws;                  // fe intermediate (1M), before At exists
    float* lf    = ws + 2097152;        // 32*HW
    float* rfeat = ws + 3145728;        // 32*HW (r2 aliases later)
    float* cost  = ws + 4194304;        // 32*HW  (raw A lower half before cost_expand)
    float* Araw  = ws + 4194304;        // 2M floats transient (= cost+bel regions)
    float* bel   = ws + 5242880;        // 32*HW
    float* bel2  = ws + 6291456;        // 32*HW
    float* lsum  = ws + 7340032;        // HW
    float* rsum  = ws + 7372800;        // HW
    float* disp  = ws + 7405568;        // HW
    float* x4    = ws + 7438336;        // 4*HW
    float* res   = ws + 7569408;        // HW

    dim3 blk(256);
    dim3 gconv(8, 16, 4);   // COUT=32
    dim3 gconv64(8, 16, 8); // COUT=64
    dim3 gconv1(8, 16, 1);  // COUT=1

    // feature extraction
    conv3x3<<<gconv, blk, 0, stream>>>(left, tmp, fe_w1, fe_b1, 3, 32, 27, 1);
    conv3x3<<<gconv, blk, 0, stream>>>(tmp, lf, fe_w2, fe_b2, 32, 32, 288, 1);
    conv3x3<<<gconv, blk, 0, stream>>>(right, tmp, fe_w1, fe_b1, 3, 32, 27, 1);
    conv3x3<<<gconv, blk, 0, stream>>>(tmp, rfeat, fe_w2, fe_b2, 32, 32, 288, 1);

    // cost volume (separated)
    chan_dot<<<dim3(HW / 256), blk, 0, stream>>>(lf, rfeat, cv_w, lsum, rsum);

    // hoisted lf-part of mp conv1 (includes mp_b1, no relu) -> Araw, then transpose -> At
    conv3x3<<<gconv64, blk, 0, stream>>>(lf, Araw, mp_w1, mp_b1, 32, 64, 297, 0);
    a_transpose<<<dim3(HW / 64), blk, 0, stream>>>(Araw, At);

    // cost + belief init (overwrites Araw region, after transpose in stream order)
    cost_expand<<<dim3(ND * HW / 256), blk, 0, stream>>>(lsum, rsum, cv_b, cost, bel);

    // 5 MP iterations, ping-pong
    dim3 gmp(1024);
    mp_iter_fast<<<gmp, blk, 0, stream>>>(At, cost, bel,  bel2, mp_w1, mp_w2, mp_b2);
    mp_iter_fast<<<gmp, blk, 0, stream>>>(At, cost, bel2, bel,  mp_w1, mp_w2, mp_b2);
    mp_iter_fast<<<gmp, blk, 0, stream>>>(At, cost, bel,  bel2, mp_w1, mp_w2, mp_b2);
    mp_iter_fast<<<gmp, blk, 0, stream>>>(At, cost, bel2, bel,  mp_w1, mp_w2, mp_b2);
    mp_iter_fast<<<gmp, blk, 0, stream>>>(At, cost, bel,  bel2, mp_w1, mp_w2, mp_b2);

    softmax_disp<<<dim3(HW / 256), blk, 0, stream>>>(bel2, disp);

    // refinement (At dead now; reuse ws+0 for r1)
    concat4<<<dim3(4 * HW / 256), blk, 0, stream>>>(left, disp, x4);
    conv3x3<<<gconv, blk, 0, stream>>>(x4, At, rf_w1, rf_b1, 4, 32, 36, 1);
    conv3x3<<<gconv, blk, 0, stream>>>(At, rfeat, rf_w2, rf_b2, 32, 32, 288, 1);
    conv3x3<<<gconv1, blk, 0, stream>>>(rfeat, res, rf_w3, rf_b3, 32, 1, 288, 0);

    final_add<<<dim3(HW / 256), blk, 0, stream>>>(disp, res, out);
}